// Round 6
// baseline (319.475 us; speedup 1.0000x reference)
//
#include <hip/hip_runtime.h>
#include <cmath>

// K[n,m] = sv^2 * sum_p (x1[n,p]-off)*(x2[m,p]-off) + sb^2,  N=M=8192, P=16.
// Output 256 MiB fp32. Fill kernel proves 6.5 TB/s on this box (~165 us/GiB).
//
// R6 = R5 resubmitted verbatim (R5 was an infrastructure failure: container
// died during acquire; the experiment never ran). R5 = R4 with the FMA4
// base-index bug fixed (R4 multiplied every x1 quad by C[c][0..3]).
//
// Theory under test (from R0-R3 pairwise elimination): four structurally
// disjoint kernels (LDS-tiled / global_load_lds / streaming plain /
// streaming nt+pipelined) all tie at kernel-side ~110-135 us (~2.4 TB/s vs
// the fill's 6.5 TB/s). Only remaining difference vs the fill: STORE-STREAM
// TOPOLOGY. The fill writes one contiguous sweeping front; our kernels had
// 2048+ resident blocks writing private tiles scattered over all 256 MiB ->
// many concurrent DRAM write streams -> page-hit collapse.
//
// R6 mimics the fill: 512 persistent blocks (2/CU, all co-resident), each
// with a FIXED 1024-col chunk (x2 fragment C[4][16] stays in registers),
// grid-striding in lockstep over 8-row bands. Active write window =
// 64 bands x 256 KiB = 16 MiB contiguous, sweeping linearly. Plain stores.
//
// Math (exact algebra, same as R2/R3 which passed):
//   C[c][p] = sv^2*(x2[m][p]-off);  bias[c] = sb^2 - off*sum_p C[c][p]
//   out[n][m] = sum_p x1[n][p]*C[c][p] + bias[c]   (raw x1 reads).

typedef float f32x4 __attribute__((ext_vector_type(4)));

#define BLOCK_THREADS 256
#define CHUNK_COLS    1024   // 4 waves * 64 lanes * 4 cols
#define BAND_ROWS     8
#define GRID_BLOCKS   512    // 2 blocks/CU -> all co-resident, lockstep sweep

__global__ __launch_bounds__(256, 2) void linear_kernel(
    const float* __restrict__ x1, const float* __restrict__ x2,
    const float* __restrict__ p_lsb, const float* __restrict__ p_lsv,
    const float* __restrict__ p_off, float* __restrict__ out,
    int n, int m)
{
    const int lane = threadIdx.x & 63;
    const int wid  = threadIdx.x >> 6;

    const int nchunks = m / CHUNK_COLS;          // 8
    const int chunk   = blockIdx.x % nchunks;    // fixed col-chunk per block
    const int b0      = blockIdx.x / nchunks;    // starting band
    const int bstep   = gridDim.x / nchunks;     // 64
    const int nbands  = n / BAND_ROWS;           // 1024

    const int c0 = chunk * CHUNK_COLS + wid * 256 + (lane << 2);

    const float off = p_off[0];
    const float sv  = expf(p_lsv[0]);
    const float sb  = expf(p_lsb[0]);
    const float sv2 = sv * sv;
    const float sb2 = sb * sb;

    // ---- One-time: x2 fragment -> registers (compile-time indices only) ----
    float C[4][16];
    f32x4 bias;
    #pragma unroll
    for (int c = 0; c < 4; ++c) {
        const f32x4* g = (const f32x4*)(x2 + (size_t)(c0 + c) * 16);
        float s = 0.0f;
        #pragma unroll
        for (int q = 0; q < 4; ++q) {
            f32x4 v = g[q];
            #pragma unroll
            for (int j = 0; j < 4; ++j) {
                const float t = sv2 * (v[j] - off);
                C[c][q * 4 + j] = t;
                s += t;
            }
        }
        bias[c] = sb2 - off * s;
    }

#define FMA4(Av, base)                                                  \
    _Pragma("unroll")                                                   \
    for (int j = 0; j < 4; ++j) {                                       \
        acc[0] = fmaf(Av[j], C[0][(base) + j], acc[0]);                 \
        acc[1] = fmaf(Av[j], C[1][(base) + j], acc[1]);                 \
        acc[2] = fmaf(Av[j], C[2][(base) + j], acc[2]);                 \
        acc[3] = fmaf(Av[j], C[3][(base) + j], acc[3]);                 \
    }

    // ---- Persistent band sweep with cross-band x1-row prefetch ----
    {
        const f32x4* ar = (const f32x4*)(x1 + (size_t)b0 * BAND_ROWS * 16);
        f32x4 a0 = ar[0], a1 = ar[1], a2 = ar[2], a3 = ar[3];

        for (int b = b0; b < nbands; b += bstep) {
            const f32x4* arB = (const f32x4*)(x1 + (size_t)b * BAND_ROWS * 16);
            const int bn = b + bstep;
            const f32x4* an = (const f32x4*)(
                x1 + (size_t)(bn < nbands ? bn : b) * BAND_ROWS * 16);
            float* orow = out + (size_t)b * BAND_ROWS * m + c0;

            #pragma unroll
            for (int r = 0; r < BAND_ROWS; ++r) {
                // Prefetch next row (last row prefetches next band's row 0).
                const f32x4* pn = (r < BAND_ROWS - 1) ? (arB + (r + 1) * 4) : an;
                const f32x4 n0 = pn[0], n1 = pn[1], n2 = pn[2], n3 = pn[3];

                f32x4 acc = bias;
                // Row x C: quad q of the row pairs with C[c][4q .. 4q+3].
                FMA4(a0, 0) FMA4(a1, 4) FMA4(a2, 8) FMA4(a3, 12)
                *(f32x4*)orow = acc;          // wave instr = 1 KiB contiguous
                orow += m;

                a0 = n0; a1 = n1; a2 = n2; a3 = n3;
            }
        }
    }
#undef FMA4
}

extern "C" void kernel_launch(void* const* d_in, const int* in_sizes, int n_in,
                              void* d_out, int out_size, void* d_ws, size_t ws_size,
                              hipStream_t stream) {
    const float* x1  = (const float*)d_in[0];
    const float* x2  = (const float*)d_in[1];
    const float* lsb = (const float*)d_in[2];
    const float* lsv = (const float*)d_in[3];
    const float* off = (const float*)d_in[4];
    float* out = (float*)d_out;

    const int n = in_sizes[0] / 16;   // 8192
    const int m = in_sizes[1] / 16;   // 8192

    linear_kernel<<<dim3(GRID_BLOCKS), BLOCK_THREADS, 0, stream>>>(
        x1, x2, lsb, lsv, off, out, n, m);
}